// Round 3
// baseline (491.467 us; speedup 1.0000x reference)
//
#include <hip/hip_runtime.h>
#include <hip/hip_bf16.h>
#include <cstdint>

#define NB 4
#define NS 2048
#define ND 1024
#define NH 16
#define NDH 64
#define NM (NB*NS)       // 8192
#define N3D (3*ND)       // 3072

typedef __attribute__((ext_vector_type(8))) short short8;
typedef __attribute__((ext_vector_type(4))) float f32x4;

__device__ __forceinline__ float bf2f(unsigned short u) {
  unsigned int i = ((unsigned int)u) << 16;
  return __builtin_bit_cast(float, i);
}
__device__ __forceinline__ unsigned short f2bf(float f) {
  unsigned int i = __builtin_bit_cast(unsigned int, f);
  i = (i + 0x7FFFu + ((i >> 16) & 1u)) >> 16;
  return (unsigned short)i;
}

#define GLD16(g, l) __builtin_amdgcn_global_load_lds( \
    (__attribute__((address_space(1))) void*)(void*)(g), \
    (__attribute__((address_space(3))) void*)(l), 16, 0, 0)

// ------------------------------------------------------------ f32 -> bf16 cast
__global__ __launch_bounds__(256) void cvt_bf16_k(
    const float* __restrict__ in, unsigned short* __restrict__ out, int n)
{
  const int i = (blockIdx.x * 256 + threadIdx.x) * 4;
  if (i + 3 < n) {
    const f32x4 v = *(const f32x4*)(in + i);
    typedef __attribute__((ext_vector_type(4))) unsigned short us4;
    us4 o = {f2bf(v[0]), f2bf(v[1]), f2bf(v[2]), f2bf(v[3])};
    *(us4*)(out + i) = o;
  }
}

// --------------------------------------------- f32 [rows][cols] -> bf16 [cols][rows]
__global__ __launch_bounds__(256) void transpose_cvt_k(
    const float* __restrict__ in, unsigned short* __restrict__ out,
    int rows, int cols)
{
  __shared__ unsigned short tile[32][33];
  const int c0 = blockIdx.x * 32, r0 = blockIdx.y * 32;
  const int tx = threadIdx.x & 31, ty = threadIdx.x >> 5;   // ty 0..7
  #pragma unroll
  for (int i = ty; i < 32; i += 8)
    tile[i][tx] = f2bf(in[(size_t)(r0 + i) * cols + (c0 + tx)]);
  __syncthreads();
  #pragma unroll
  for (int i = ty; i < 32; i += 8)
    out[(size_t)(c0 + i) * rows + (r0 + tx)] = tile[tx][i];
}

// ---------------------------------- V columns of qkv -> Vt[bh][d=64][s=2048]
__global__ __launch_bounds__(256) void vt_transpose_k(
    const unsigned short* __restrict__ qkv, unsigned short* __restrict__ vt)
{
  __shared__ unsigned short tile[32][33];
  const int dt = blockIdx.x & 1;           // 2 d-tiles
  const int st = (blockIdx.x >> 1) & 63;   // 64 s-tiles
  const int bh = blockIdx.x >> 7;          // 64 (b,h)
  const int b = bh >> 4, h = bh & 15;
  const int tx = threadIdx.x & 31, ty = threadIdx.x >> 5;
  const int s0 = st * 32, d0 = dt * 32;
  const unsigned short* src = qkv + (size_t)b * NS * N3D + 2 * ND + h * NDH;
  #pragma unroll
  for (int i = ty; i < 32; i += 8)
    tile[i][tx] = src[(size_t)(s0 + i) * N3D + d0 + tx];
  __syncthreads();
  unsigned short* dst = vt + (size_t)bh * NDH * NS;
  #pragma unroll
  for (int i = ty; i < 32; i += 8)
    dst[(size_t)(d0 + i) * NS + s0 + tx] = tile[tx][i];
}

// ------------------------------------------------- GEMM  C = A * Bt^T + bias
// A[M][K] bf16 row-major, Bt[N][K] bf16 row-major, f32 bias. 128x128 tile,
// BK=32, 4 waves (2x2 of 64x64), global_load_lds staging (m97 structure).
template<bool OUT_F32>
__global__ __launch_bounds__(256) void gemm_bt_bias(
    const unsigned short* __restrict__ A,
    const unsigned short* __restrict__ Bt,
    const float* __restrict__ bias,
    unsigned short* __restrict__ Cb,
    float* __restrict__ Cf,
    int M, int N, int K)
{
  __shared__ __align__(16) unsigned short Alds[128 * 32];
  __shared__ __align__(16) unsigned short Blds[128 * 32];
  const int nbn = N >> 7;
  const int bm = blockIdx.x / nbn, bn = blockIdx.x % nbn;
  const int m0 = bm << 7, n0 = bn << 7;
  const int w = threadIdx.x >> 6, l = threadIdx.x & 63;
  const int wr = w >> 1, wc = w & 1;
  const int lr = l & 15, lg = l >> 4;

  const unsigned short* gA = A + (size_t)(m0 + w * 32 + (l >> 2)) * K + (l & 3) * 8;
  const unsigned short* gB = Bt + (size_t)(n0 + w * 32 + (l >> 2)) * K + (l & 3) * 8;
  unsigned short* lA = Alds + (w * 32) * 32;   // wave-uniform LDS base
  unsigned short* lB = Blds + (w * 32) * 32;

  f32x4 acc[4][4] = {};

  for (int k0 = 0; k0 < K; k0 += 32) {
    GLD16(gA + k0, lA);
    GLD16(gA + k0 + (size_t)16 * K, lA + 16 * 32);
    GLD16(gB + k0, lB);
    GLD16(gB + k0 + (size_t)16 * K, lB + 16 * 32);
    __syncthreads();

    short8 a[4], b[4];
    #pragma unroll
    for (int i = 0; i < 4; ++i)
      a[i] = *(const short8*)(Alds + (wr * 64 + i * 16 + lr) * 32 + lg * 8);
    #pragma unroll
    for (int j = 0; j < 4; ++j)
      b[j] = *(const short8*)(Blds + (wc * 64 + j * 16 + lr) * 32 + lg * 8);

    #pragma unroll
    for (int i = 0; i < 4; ++i)
      #pragma unroll
      for (int j = 0; j < 4; ++j)
        acc[i][j] = __builtin_amdgcn_mfma_f32_16x16x32_bf16(a[i], b[j], acc[i][j], 0, 0, 0);
    __syncthreads();
  }

  #pragma unroll
  for (int j = 0; j < 4; ++j) {
    const int col = n0 + wc * 64 + j * 16 + lr;
    const float bv = bias[col];
    #pragma unroll
    for (int i = 0; i < 4; ++i) {
      #pragma unroll
      for (int r = 0; r < 4; ++r) {
        const int row = m0 + wr * 64 + i * 16 + lg * 4 + r;
        const float v = acc[i][j][r] + bv;
        if (OUT_F32) Cf[(size_t)row * N + col] = v;
        else         Cb[(size_t)row * N + col] = f2bf(v);
      }
    }
  }
}

// ----------------------------------------------------- causal flash attention
// qkv[B*S][3D] bf16 (Q,K); Vt[bh][64][2048] bf16 (V transposed).
// Per wave: 32 q-rows of one (b,h); 32-key tiles; online softmax.
__global__ __launch_bounds__(256) void attn_fwd(
    const unsigned short* __restrict__ qkv,
    const unsigned short* __restrict__ Vt,
    unsigned short* __restrict__ out)
{
  // P tile per wave per q-subtile: 16 rows x 32 keys, row stride 40 u16 (80B,
  // 16B-aligned for ds_read_b128, breaks the 8-way bank conflict of stride 32)
  __shared__ __align__(16) unsigned short Plds[4][2][16 * 40];
  const int blk = blockIdx.x;
  const int bh = blk >> 4;               // 64 (b,h) pairs
  const int qt = blk & 15;               // 16 q-tiles of 128 rows
  const int b = bh >> 4, h = bh & 15;
  const int w = threadIdx.x >> 6, l = threadIdx.x & 63;
  const int lr = l & 15, lg = l >> 4;
  const int q0 = qt * 128 + w * 32;

  const size_t rs = N3D;
  const unsigned short* Qb = qkv + (size_t)b * NS * rs + (size_t)h * NDH;
  const unsigned short* Kb = Qb + ND;
  const unsigned short* Vb = Vt + (size_t)bh * NDH * NS;

  // Q fragments: tile t rows q0+t*16+lr, d-halves
  short8 qf[2][2];
  #pragma unroll
  for (int t = 0; t < 2; ++t) {
    const unsigned short* qrow = Qb + (size_t)(q0 + t * 16 + lr) * rs + lg * 8;
    qf[t][0] = *(const short8*)(qrow);
    qf[t][1] = *(const short8*)(qrow + 32);
  }

  float m_run[2][4], l_run[2][4];
  f32x4 o[2][4];
  f32x4 zero = {0.f, 0.f, 0.f, 0.f};
  #pragma unroll
  for (int t = 0; t < 2; ++t)
    #pragma unroll
    for (int r = 0; r < 4; ++r) { m_run[t][r] = -__builtin_inff(); l_run[t][r] = 0.f; }
  #pragma unroll
  for (int t = 0; t < 2; ++t)
    #pragma unroll
    for (int nb = 0; nb < 4; ++nb) o[t][nb] = zero;

  const int ktmax = (q0 + 31) >> 5;
  for (int kt = 0; kt <= ktmax; ++kt) {
    const int kbase = kt << 5;

    // V fragments (vector loads from Vt) — issue first so latency hides
    short8 vf[4];
    #pragma unroll
    for (int nb = 0; nb < 4; ++nb)
      vf[nb] = *(const short8*)(Vb + (size_t)(nb * 16 + lr) * NS + kbase + lg * 8);

    // K^T fragments: lane holds K[kbase+sub*16+lr][lg*8+j]
    const unsigned short* krow = Kb + (size_t)(kbase + lr) * rs + lg * 8;
    short8 k00 = *(const short8*)(krow);
    short8 k01 = *(const short8*)(krow + 32);
    short8 k10 = *(const short8*)(krow + 16 * rs);
    short8 k11 = *(const short8*)(krow + 16 * rs + 32);

    f32x4 s[2][2];
    #pragma unroll
    for (int t = 0; t < 2; ++t) {
      s[t][0] = zero; s[t][1] = zero;
      s[t][0] = __builtin_amdgcn_mfma_f32_16x16x32_bf16(qf[t][0], k00, s[t][0], 0, 0, 0);
      s[t][0] = __builtin_amdgcn_mfma_f32_16x16x32_bf16(qf[t][1], k01, s[t][0], 0, 0, 0);
      s[t][1] = __builtin_amdgcn_mfma_f32_16x16x32_bf16(qf[t][0], k10, s[t][1], 0, 0, 0);
      s[t][1] = __builtin_amdgcn_mfma_f32_16x16x32_bf16(qf[t][1], k11, s[t][1], 0, 0, 0);
    }

    // mask -> scale -> online softmax.  D-layout: row=lg*4+r, col=lr
    #pragma unroll
    for (int t = 0; t < 2; ++t) {
      float p0[4], p1[4], sf[4];
      #pragma unroll
      for (int r = 0; r < 4; ++r) {
        const int qi = q0 + t * 16 + lg * 4 + r;
        float t0 = (kbase + lr) <= qi ? s[t][0][r] * 0.125f : -__builtin_inff();
        float t1 = (kbase + 16 + lr) <= qi ? s[t][1][r] * 0.125f : -__builtin_inff();
        float mx = fmaxf(t0, t1);
        #pragma unroll
        for (int d = 1; d < 16; d <<= 1) mx = fmaxf(mx, __shfl_xor(mx, d));
        const float mnew = fmaxf(m_run[t][r], mx);
        sf[r] = __expf(m_run[t][r] - mnew);
        m_run[t][r] = mnew;
        p0[r] = __expf(t0 - mnew);
        p1[r] = __expf(t1 - mnew);
        float rsum = p0[r] + p1[r];
        #pragma unroll
        for (int d = 1; d < 16; d <<= 1) rsum += __shfl_xor(rsum, d);
        l_run[t][r] = l_run[t][r] * sf[r] + rsum;
      }
      #pragma unroll
      for (int nb = 0; nb < 4; ++nb)
        #pragma unroll
        for (int r = 0; r < 4; ++r) o[t][nb][r] *= sf[r];

      // transpose P (D-layout) -> A-frag layout through per-wave LDS
      unsigned short* pl = &Plds[w][t][0];
      #pragma unroll
      for (int r = 0; r < 4; ++r) {
        pl[(lg * 4 + r) * 40 + lr]      = f2bf(p0[r]);
        pl[(lg * 4 + r) * 40 + 16 + lr] = f2bf(p1[r]);
      }
    }
    asm volatile("s_waitcnt lgkmcnt(0)" ::: "memory");   // same-wave, no barrier
    __builtin_amdgcn_sched_barrier(0);
    #pragma unroll
    for (int t = 0; t < 2; ++t) {
      short8 pf = *(const short8*)(&Plds[w][t][0] + lr * 40 + lg * 8);
      #pragma unroll
      for (int nb = 0; nb < 4; ++nb)
        o[t][nb] = __builtin_amdgcn_mfma_f32_16x16x32_bf16(pf, vf[nb], o[t][nb], 0, 0, 0);
    }
  }

  #pragma unroll
  for (int t = 0; t < 2; ++t)
    #pragma unroll
    for (int r = 0; r < 4; ++r) {
      const int qi = q0 + t * 16 + lg * 4 + r;
      const float inv = 1.0f / l_run[t][r];
      #pragma unroll
      for (int nb = 0; nb < 4; ++nb)
        out[(size_t)(b * NS + qi) * ND + h * NDH + nb * 16 + lr] = f2bf(o[t][nb][r] * inv);
    }
}

// --------------------------------------------------------------------- launch
extern "C" void kernel_launch(void* const* d_in, const int* in_sizes, int n_in,
                              void* d_out, int out_size, void* d_ws, size_t ws_size,
                              hipStream_t stream) {
  const float* x     = (const float*)d_in[0];
  const float* w_in  = (const float*)d_in[1];
  const float* b_in  = (const float*)d_in[2];
  const float* w_out = (const float*)d_in[3];
  const float* b_out = (const float*)d_in[4];
  float* out = (float*)d_out;

  char* ws = (char*)d_ws;
  size_t off = 0;
  unsigned short* x_bf    = (unsigned short*)(ws + off); off += (size_t)NM * ND * 2;    // 16 MiB
  unsigned short* qkv     = (unsigned short*)(ws + off); off += (size_t)NM * N3D * 2;   // 48 MiB
  unsigned short* attn    = (unsigned short*)(ws + off); off += (size_t)NM * ND * 2;    // 16 MiB
  unsigned short* w_in_t  = (unsigned short*)(ws + off); off += (size_t)N3D * ND * 2;   //  6 MiB
  unsigned short* w_out_t = (unsigned short*)(ws + off); off += (size_t)ND * ND * 2;    //  2 MiB
  // Vt aliases x_bf: x_bf is dead after GEMM1, vt_transpose runs after GEMM1.
  unsigned short* vt = x_bf;                                                            // 16 MiB

  // x -> bf16
  cvt_bf16_k<<<dim3((NM * ND) / (256 * 4)), 256, 0, stream>>>(x, x_bf, NM * ND);
  // weight transposes + cast: w[K][N] f32 -> wt[N][K] bf16
  transpose_cvt_k<<<dim3(N3D / 32, ND / 32), 256, 0, stream>>>(w_in, w_in_t, ND, N3D);
  transpose_cvt_k<<<dim3(ND / 32, ND / 32), 256, 0, stream>>>(w_out, w_out_t, ND, ND);

  // qkv = x @ w_in + b_in            (bf16 out)
  gemm_bt_bias<false><<<dim3((NM / 128) * (N3D / 128)), 256, 0, stream>>>(
      x_bf, w_in_t, b_in, qkv, nullptr, NM, N3D, ND);

  // V -> Vt (transposed per head)
  vt_transpose_k<<<dim3(64 * 64 * 2), 256, 0, stream>>>(qkv, vt);

  // attention
  attn_fwd<<<dim3((NB * NH) * (NS / 128)), 256, 0, stream>>>(qkv, vt, attn);

  // out = attn @ w_out + b_out       (f32 out)
  gemm_bt_bias<true><<<dim3((NM / 128) * (ND / 128)), 256, 0, stream>>>(
      attn, w_out_t, b_out, nullptr, out, NM, ND, ND);
}

// Round 4
// 267.485 us; speedup vs baseline: 1.8374x; 1.8374x over previous
//
#include <hip/hip_runtime.h>
#include <hip/hip_bf16.h>
#include <cstdint>

#define NB 4
#define NS 2048
#define ND 1024
#define NH 16
#define NDH 64
#define NM (NB*NS)       // 8192
#define N3D (3*ND)       // 3072

typedef __attribute__((ext_vector_type(8))) short short8;
typedef __attribute__((ext_vector_type(4))) float f32x4;
typedef __attribute__((ext_vector_type(4))) unsigned short us4;

__device__ __forceinline__ float bf2f(unsigned short u) {
  unsigned int i = ((unsigned int)u) << 16;
  return __builtin_bit_cast(float, i);
}
__device__ __forceinline__ unsigned short f2bf(float f) {
  unsigned int i = __builtin_bit_cast(unsigned int, f);
  i = (i + 0x7FFFu + ((i >> 16) & 1u)) >> 16;
  return (unsigned short)i;
}

#define GLD16(g, l) __builtin_amdgcn_global_load_lds( \
    (__attribute__((address_space(1))) void*)(void*)(g), \
    (__attribute__((address_space(3))) void*)(l), 16, 0, 0)

// ------------------------------------------------------------ f32 -> bf16 cast
__global__ __launch_bounds__(256) void cvt_bf16_k(
    const float* __restrict__ in, unsigned short* __restrict__ out, int n)
{
  const int i = (blockIdx.x * 256 + threadIdx.x) * 4;
  if (i + 3 < n) {
    const f32x4 v = *(const f32x4*)(in + i);
    us4 o = {f2bf(v[0]), f2bf(v[1]), f2bf(v[2]), f2bf(v[3])};
    *(us4*)(out + i) = o;
  }
}

// --------------------------------------------- f32 [rows][cols] -> bf16 [cols][rows]
__global__ __launch_bounds__(256) void transpose_cvt_k(
    const float* __restrict__ in, unsigned short* __restrict__ out,
    int rows, int cols)
{
  __shared__ unsigned short tile[32][33];
  const int c0 = blockIdx.x * 32, r0 = blockIdx.y * 32;
  const int tx = threadIdx.x & 31, ty = threadIdx.x >> 5;   // ty 0..7
  #pragma unroll
  for (int i = ty; i < 32; i += 8)
    tile[i][tx] = f2bf(in[(size_t)(r0 + i) * cols + (c0 + tx)]);
  __syncthreads();
  #pragma unroll
  for (int i = ty; i < 32; i += 8)
    out[(size_t)(c0 + i) * rows + (r0 + tx)] = tile[tx][i];
}

// ---------------------------------- V columns of qkv -> Vt[bh][d=64][s=2048]
__global__ __launch_bounds__(256) void vt_transpose_k(
    const unsigned short* __restrict__ qkv, unsigned short* __restrict__ vt)
{
  __shared__ unsigned short tile[32][33];
  const int dt = blockIdx.x & 1;           // 2 d-tiles
  const int st = (blockIdx.x >> 1) & 63;   // 64 s-tiles
  const int bh = blockIdx.x >> 7;          // 64 (b,h)
  const int b = bh >> 4, h = bh & 15;
  const int tx = threadIdx.x & 31, ty = threadIdx.x >> 5;
  const int s0 = st * 32, d0 = dt * 32;
  const unsigned short* src = qkv + (size_t)b * NS * N3D + 2 * ND + h * NDH;
  #pragma unroll
  for (int i = ty; i < 32; i += 8)
    tile[i][tx] = src[(size_t)(s0 + i) * N3D + d0 + tx];
  __syncthreads();
  unsigned short* dst = vt + (size_t)bh * NDH * NS;
  #pragma unroll
  for (int i = ty; i < 32; i += 8)
    dst[(size_t)(d0 + i) * NS + s0 + tx] = tile[tx][i];
}

// ------------------------------------------------- GEMM  C = A * Bt^T + bias
// A[M][K] bf16 row-major, Bt[N][K] bf16 row-major, f32 bias. 128x128 tile,
// BK=32, 4 waves (2x2 of 64x64), global_load_lds staging (m97 structure).
template<bool OUT_F32>
__global__ __launch_bounds__(256) void gemm_bt_bias(
    const unsigned short* __restrict__ A,
    const unsigned short* __restrict__ Bt,
    const float* __restrict__ bias,
    unsigned short* __restrict__ Cb,
    float* __restrict__ Cf,
    int M, int N, int K)
{
  __shared__ __align__(16) unsigned short Alds[128 * 32];
  __shared__ __align__(16) unsigned short Blds[128 * 32];
  const int nbn = N >> 7;
  const int bm = blockIdx.x / nbn, bn = blockIdx.x % nbn;
  const int m0 = bm << 7, n0 = bn << 7;
  const int w = threadIdx.x >> 6, l = threadIdx.x & 63;
  const int wr = w >> 1, wc = w & 1;
  const int lr = l & 15, lg = l >> 4;

  const unsigned short* gA = A + (size_t)(m0 + w * 32 + (l >> 2)) * K + (l & 3) * 8;
  const unsigned short* gB = Bt + (size_t)(n0 + w * 32 + (l >> 2)) * K + (l & 3) * 8;
  unsigned short* lA = Alds + (w * 32) * 32;   // wave-uniform LDS base
  unsigned short* lB = Blds + (w * 32) * 32;

  f32x4 acc[4][4] = {};

  for (int k0 = 0; k0 < K; k0 += 32) {
    GLD16(gA + k0, lA);
    GLD16(gA + k0 + (size_t)16 * K, lA + 16 * 32);
    GLD16(gB + k0, lB);
    GLD16(gB + k0 + (size_t)16 * K, lB + 16 * 32);
    __syncthreads();

    short8 a[4], b[4];
    #pragma unroll
    for (int i = 0; i < 4; ++i)
      a[i] = *(const short8*)(Alds + (wr * 64 + i * 16 + lr) * 32 + lg * 8);
    #pragma unroll
    for (int j = 0; j < 4; ++j)
      b[j] = *(const short8*)(Blds + (wc * 64 + j * 16 + lr) * 32 + lg * 8);

    #pragma unroll
    for (int i = 0; i < 4; ++i)
      #pragma unroll
      for (int j = 0; j < 4; ++j)
        acc[i][j] = __builtin_amdgcn_mfma_f32_16x16x32_bf16(a[i], b[j], acc[i][j], 0, 0, 0);
    __syncthreads();
  }

  #pragma unroll
  for (int j = 0; j < 4; ++j) {
    const int col = n0 + wc * 64 + j * 16 + lr;
    const float bv = bias[col];
    #pragma unroll
    for (int i = 0; i < 4; ++i) {
      #pragma unroll
      for (int r = 0; r < 4; ++r) {
        const int row = m0 + wr * 64 + i * 16 + lg * 4 + r;
        const float v = acc[i][j][r] + bv;
        if (OUT_F32) Cf[(size_t)row * N + col] = v;
        else         Cb[(size_t)row * N + col] = f2bf(v);
      }
    }
  }
}

// ----------------------------------------------------- causal flash attention
// Swapped QK^T: S^T = mfma(K,Q) so each lane owns a full 16-score slice of ONE
// q-row per (t,ks) -> softmax reduce = local tree + 2 shuffles (over lg axis).
// KVBLK=64. T13 defer-max (THR=8). P transposed to LDS via packed b64 writes,
// XOR-swizzled 128B rows. LPT block order (heavy q-tiles first).
__global__ __launch_bounds__(256) void attn_fwd(
    const unsigned short* __restrict__ qkv,
    const unsigned short* __restrict__ Vt,
    unsigned short* __restrict__ out)
{
  __shared__ __align__(16) char Plds[4][32 * 128];   // per-wave [32 q][64 k] bf16, swizzled
  const int blk = blockIdx.x;
  const int bh = blk & 63;               // interleave bh fastest
  const int qt = 15 - (blk >> 6);        // LPT: heaviest q-tiles dispatched first
  const int b = bh >> 4, h = bh & 15;
  const int w = threadIdx.x >> 6, l = threadIdx.x & 63;
  const int lr = l & 15, lg = l >> 4;
  const int q0 = qt * 128 + w * 32;

  const size_t rs = N3D;
  const unsigned short* Qb = qkv + (size_t)b * NS * rs + (size_t)h * NDH;
  const unsigned short* Kb = Qb + ND;
  const unsigned short* Vb = Vt + (size_t)bh * NDH * NS;

  // Q fragments: lane holds Q[q0+t*16+lr][lg*8+j (+32)]
  short8 qf[2][2];
  #pragma unroll
  for (int t = 0; t < 2; ++t) {
    const unsigned short* qrow = Qb + (size_t)(q0 + t * 16 + lr) * rs + lg * 8;
    qf[t][0] = *(const short8*)(qrow);
    qf[t][1] = *(const short8*)(qrow + 32);
  }

  float m_run[2], l_run[2];
  f32x4 o[2][4] = {};
  m_run[0] = m_run[1] = -__builtin_inff();
  l_run[0] = l_run[1] = 0.f;

  char* pw = &Plds[w][0];
  const int swz = (lr & 7) << 4;

  const int ktmax = (q0 + 31) >> 6;
  for (int kt = 0; kt <= ktmax; ++kt) {
    const int kbase = kt << 6;

    // V fragments (B-operand of PV): lane holds V[kbase+kk*32+lg*8+j][nb*16+lr]
    short8 vf[4][2];
    #pragma unroll
    for (int nb = 0; nb < 4; ++nb)
      #pragma unroll
      for (int kk = 0; kk < 2; ++kk)
        vf[nb][kk] = *(const short8*)(Vb + (size_t)(nb * 16 + lr) * NS + kbase + kk * 32 + lg * 8);

    // K loads + swapped QK^T: s[ks][t] = S^T[key=kbase+ks*16+lg*4+r][q=q0+t*16+lr]
    f32x4 s[4][2] = {};
    #pragma unroll
    for (int ks = 0; ks < 4; ++ks) {
      const unsigned short* krow = Kb + (size_t)(kbase + ks * 16 + lr) * rs + lg * 8;
      short8 k0 = *(const short8*)(krow);
      short8 k1 = *(const short8*)(krow + 32);
      #pragma unroll
      for (int t = 0; t < 2; ++t) {
        s[ks][t] = __builtin_amdgcn_mfma_f32_16x16x32_bf16(k0, qf[t][0], s[ks][t], 0, 0, 0);
        s[ks][t] = __builtin_amdgcn_mfma_f32_16x16x32_bf16(k1, qf[t][1], s[ks][t], 0, 0, 0);
      }
    }

    const bool domask = (kbase + 63 > q0);   // wave-uniform
    #pragma unroll
    for (int t = 0; t < 2; ++t) {
      const int qi = q0 + t * 16 + lr;
      float v[16];
      #pragma unroll
      for (int ks = 0; ks < 4; ++ks)
        #pragma unroll
        for (int r = 0; r < 4; ++r)
          v[ks * 4 + r] = s[ks][t][r] * 0.125f;
      if (domask) {
        #pragma unroll
        for (int ks = 0; ks < 4; ++ks)
          #pragma unroll
          for (int r = 0; r < 4; ++r)
            if (kbase + ks * 16 + lg * 4 + r > qi) v[ks * 4 + r] = -__builtin_inff();
      }
      // row max: local tree + 2 shuffles over the lg axis
      float a0 = fmaxf(v[0], v[1]),  a1 = fmaxf(v[2], v[3]);
      float a2 = fmaxf(v[4], v[5]),  a3 = fmaxf(v[6], v[7]);
      float a4 = fmaxf(v[8], v[9]),  a5 = fmaxf(v[10], v[11]);
      float a6 = fmaxf(v[12], v[13]), a7 = fmaxf(v[14], v[15]);
      float b0 = fmaxf(a0, a1), b1 = fmaxf(a2, a3), b2 = fmaxf(a4, a5), b3 = fmaxf(a6, a7);
      float mx = fmaxf(fmaxf(b0, b1), fmaxf(b2, b3));
      mx = fmaxf(mx, __shfl_xor(mx, 16));
      mx = fmaxf(mx, __shfl_xor(mx, 32));

      const float mold = m_run[t];
      if (__any(mx > mold + 8.0f)) {           // T13 defer-max
        const float mnew = fmaxf(mold, mx);
        const float sf = __expf(mold - mnew);
        m_run[t] = mnew;
        l_run[t] *= sf;
        #pragma unroll
        for (int rr = 0; rr < 4; ++rr) {
          const float sfo = __shfl(sf, lg * 4 + rr);
          #pragma unroll
          for (int nb = 0; nb < 4; ++nb) o[t][nb][rr] *= sfo;
        }
      }
      const float mc = m_run[t];
      float p[16];
      #pragma unroll
      for (int i = 0; i < 16; ++i) p[i] = __expf(v[i] - mc);
      float s0 = (p[0] + p[1]) + (p[2] + p[3]);
      float s1 = (p[4] + p[5]) + (p[6] + p[7]);
      float s2 = (p[8] + p[9]) + (p[10] + p[11]);
      float s3 = (p[12] + p[13]) + (p[14] + p[15]);
      float rsum = (s0 + s1) + (s2 + s3);
      rsum += __shfl_xor(rsum, 16);
      rsum += __shfl_xor(rsum, 32);
      l_run[t] += rsum;

      // P write: lane's 4 consecutive k at row q -> packed b64, swizzled
      #pragma unroll
      for (int ks = 0; ks < 4; ++ks) {
        us4 pk = {f2bf(p[ks * 4]), f2bf(p[ks * 4 + 1]), f2bf(p[ks * 4 + 2]), f2bf(p[ks * 4 + 3])};
        *(us4*)(pw + ((((t * 16 + lr) * 128) + ks * 32 + lg * 8) ^ swz)) = pk;
      }
    }

    asm volatile("s_waitcnt lgkmcnt(0)" ::: "memory");   // same-wave write->read
    __builtin_amdgcn_sched_barrier(0);

    #pragma unroll
    for (int t = 0; t < 2; ++t)
      #pragma unroll
      for (int kk = 0; kk < 2; ++kk) {
        short8 pf = *(const short8*)(pw + ((((t * 16 + lr) * 128) + kk * 64 + lg * 16) ^ swz));
        #pragma unroll
        for (int nb = 0; nb < 4; ++nb)
          o[t][nb] = __builtin_amdgcn_mfma_f32_16x16x32_bf16(pf, vf[nb][kk], o[t][nb], 0, 0, 0);
      }
  }

  // epilogue: o rows are q=t*16+lg*4+rr; fetch row sum via bpermute
  #pragma unroll
  for (int t = 0; t < 2; ++t)
    #pragma unroll
    for (int rr = 0; rr < 4; ++rr) {
      const float lq = __shfl(l_run[t], lg * 4 + rr);
      const float inv = 1.0f / lq;
      const int qi = q0 + t * 16 + lg * 4 + rr;
      #pragma unroll
      for (int nb = 0; nb < 4; ++nb)
        out[(size_t)(b * NS + qi) * ND + h * NDH + nb * 16 + lr] = f2bf(o[t][nb][rr] * inv);
    }
}

// --------------------------------------------------------------------- launch
extern "C" void kernel_launch(void* const* d_in, const int* in_sizes, int n_in,
                              void* d_out, int out_size, void* d_ws, size_t ws_size,
                              hipStream_t stream) {
  const float* x     = (const float*)d_in[0];
  const float* w_in  = (const float*)d_in[1];
  const float* b_in  = (const float*)d_in[2];
  const float* w_out = (const float*)d_in[3];
  const float* b_out = (const float*)d_in[4];
  float* out = (float*)d_out;

  char* ws = (char*)d_ws;
  size_t off = 0;
  unsigned short* x_bf    = (unsigned short*)(ws + off); off += (size_t)NM * ND * 2;    // 16 MiB
  unsigned short* qkv     = (unsigned short*)(ws + off); off += (size_t)NM * N3D * 2;   // 48 MiB
  unsigned short* attn    = (unsigned short*)(ws + off); off += (size_t)NM * ND * 2;    // 16 MiB
  unsigned short* w_in_t  = (unsigned short*)(ws + off); off += (size_t)N3D * ND * 2;   //  6 MiB
  unsigned short* w_out_t = (unsigned short*)(ws + off); off += (size_t)ND * ND * 2;    //  2 MiB
  // Vt aliases x_bf: x_bf is dead after GEMM1, vt_transpose runs after GEMM1.
  unsigned short* vt = x_bf;                                                            // 16 MiB

  // x -> bf16
  cvt_bf16_k<<<dim3((NM * ND) / (256 * 4)), 256, 0, stream>>>(x, x_bf, NM * ND);
  // weight transposes + cast: w[K][N] f32 -> wt[N][K] bf16
  transpose_cvt_k<<<dim3(N3D / 32, ND / 32), 256, 0, stream>>>(w_in, w_in_t, ND, N3D);
  transpose_cvt_k<<<dim3(ND / 32, ND / 32), 256, 0, stream>>>(w_out, w_out_t, ND, ND);

  // qkv = x @ w_in + b_in            (bf16 out)
  gemm_bt_bias<false><<<dim3((NM / 128) * (N3D / 128)), 256, 0, stream>>>(
      x_bf, w_in_t, b_in, qkv, nullptr, NM, N3D, ND);

  // V -> Vt (transposed per head)
  vt_transpose_k<<<dim3(64 * 64 * 2), 256, 0, stream>>>(qkv, vt);

  // attention
  attn_fwd<<<dim3(64 * 16), 256, 0, stream>>>(qkv, vt, attn);

  // out = attn @ w_out + b_out       (f32 out)
  gemm_bt_bias<true><<<dim3((NM / 128) * (ND / 128)), 256, 0, stream>>>(
      attn, w_out_t, b_out, nullptr, out, NM, ND, ND);
}